// Round 5
// baseline (633.713 us; speedup 1.0000x reference)
//
#include <hip/hip_runtime.h>
#include <hip/hip_bf16.h>

typedef unsigned int u32;
typedef unsigned short u16;

// ---- bf16 helpers (fp32 <-> bf16 with RNE) ----
__device__ __forceinline__ float bfl(u32 v) { return __uint_as_float(v << 16); }
__device__ __forceinline__ float bfh(u32 v) { return __uint_as_float(v & 0xffff0000u); }
__device__ __forceinline__ u16 f2bf(float f) {
    u32 u = __float_as_uint(f);
    u32 r = (u + 0x7fffu + ((u >> 16) & 1u)) >> 16;
    return (u16)r;
}

#define HW 16384          // 128*128
#define NCH 496           // 16*31 combined channels (m = t*31 + c)

// ============================================================================
// K1 v3: fused pointwise qkv (16->48) + depthwise 3x3 per (b,c) plane.
// Block = 6-output-row x 128-col strip; 256 threads as 2 rows x 128 cols.
// 8 halo rows of x in registers (xv[4][16]). Per (group g, quad-pair qp):
// stage 8 channels' pointwise in LDS float4[2][8][128] = 32 KB (was 64 KB ->
// occupancy 2->4 blocks/CU; round-3 counters showed occ 21.8%, VALU 30%,
// HBM 12% = latency-bound on LDS cap). Depthwise 3x3 from LDS; fully
// coalesced u16 row stores.
// ============================================================================
__global__ __launch_bounds__(256) void k1_qkvdw(
    const float* __restrict__ x, const float* __restrict__ wq,
    const float* __restrict__ wd, u16* __restrict__ qw, u16* __restrict__ kw,
    u16* __restrict__ vw)
{
    const int s = blockIdx.x, c = blockIdx.y, b = blockIdx.z;
    const int tid = threadIdx.x;
    const int tr = tid >> 7, tc = tid & 127;
    const int r0 = s * 6 - 1;                 // first halo row

    // load 8 halo rows (2 per slot) x 16 channels of x
    float xv[4][16];
    #pragma unroll
    for (int sl = 0; sl < 4; sl++) {
        const int row = r0 + 2 * sl + tr;
        const bool ok = (row >= 0) && (row < 128);
        const float* xp = x + ((size_t)b * 496 + c) * HW + row * 128 + tc;
        #pragma unroll
        for (int t = 0; t < 16; t++)
            xv[sl][t] = ok ? xp[(size_t)t * 31 * HW] : 0.f;
    }

    __shared__ float4 pws[2][8][128];         // [quad-in-pair][halo row][col] 32 KB

    for (int g = 0; g < 3; g++) {
        u16* dst = (g == 0) ? qw : (g == 1) ? kw : vw;
        for (int qp = 0; qp < 2; qp++) {
            __syncthreads();                  // prior depthwise reads complete
            // pointwise for 8 channels (quads 2qp, 2qp+1) at the 8 halo rows
            #pragma unroll
            for (int sl = 0; sl < 4; sl++) {
                float pv[8];
                #pragma unroll
                for (int o8 = 0; o8 < 8; o8++) {
                    const int oo = qp * 8 + o8;
                    float a = 0.f;
                    #pragma unroll
                    for (int ci = 0; ci < 16; ci++)
                        a = fmaf(wq[(g * 16 + oo) * 16 + ci], xv[sl][ci], a);
                    pv[o8] = a;
                }
                const int lr = 2 * sl + tr;
                pws[0][lr][tc] = make_float4(pv[0], pv[1], pv[2], pv[3]);
                pws[1][lr][tc] = make_float4(pv[4], pv[5], pv[6], pv[7]);
            }
            __syncthreads();

            // depthwise 3x3 at the 6 output rows (3 per thread-row)
            #pragma unroll
            for (int k = 0; k < 3; k++) {
                const int lr = 1 + 2 * k + tr;    // 1..6 local halo row
                const int grow = r0 + lr;         // global output row
                if (grow < 128) {                 // trims only the last strip
                    #pragma unroll
                    for (int lq = 0; lq < 2; lq++) {
                        const int q4 = qp * 2 + lq;
                        const int o0 = g * 16 + q4 * 4;
                        float a0 = 0.f, a1 = 0.f, a2 = 0.f, a3 = 0.f;
                        #pragma unroll
                        for (int dy = 0; dy < 3; dy++) {
                            const float4 Cv = pws[lq][lr + dy - 1][tc];
                            const float4 Lv = (tc > 0)   ? pws[lq][lr + dy - 1][tc - 1] : make_float4(0.f,0.f,0.f,0.f);
                            const float4 Rv = (tc < 127) ? pws[lq][lr + dy - 1][tc + 1] : make_float4(0.f,0.f,0.f,0.f);
                            const int kb9 = dy * 3;
                            a0 = fmaf(Lv.x, wd[(o0+0)*9+kb9+0], fmaf(Cv.x, wd[(o0+0)*9+kb9+1], fmaf(Rv.x, wd[(o0+0)*9+kb9+2], a0)));
                            a1 = fmaf(Lv.y, wd[(o0+1)*9+kb9+0], fmaf(Cv.y, wd[(o0+1)*9+kb9+1], fmaf(Rv.y, wd[(o0+1)*9+kb9+2], a1)));
                            a2 = fmaf(Lv.z, wd[(o0+2)*9+kb9+0], fmaf(Cv.z, wd[(o0+2)*9+kb9+1], fmaf(Rv.z, wd[(o0+2)*9+kb9+2], a2)));
                            a3 = fmaf(Lv.w, wd[(o0+3)*9+kb9+0], fmaf(Cv.w, wd[(o0+3)*9+kb9+1], fmaf(Rv.w, wd[(o0+3)*9+kb9+2], a3)));
                        }
                        const size_t pbase = (size_t)grow * 128 + tc;
                        dst[((size_t)b * NCH + (q4*4+0) * 31 + c) * HW + pbase] = f2bf(a0);
                        dst[((size_t)b * NCH + (q4*4+1) * 31 + c) * HW + pbase] = f2bf(a1);
                        dst[((size_t)b * NCH + (q4*4+2) * 31 + c) * HW + pbase] = f2bf(a2);
                        dst[((size_t)b * NCH + (q4*4+3) * 31 + c) * HW + pbase] = f2bf(a3);
                    }
                }
            }
        }
    }
}

// ============================================================================
// K2 v2: Gram G[b][31][31] = Q K^T over N=262144, plus ssq (L2-norm numerators)
// accumulated during staging. Block = (px-chunk of 1024, j, b). Staging:
// thread (srow=tid>>3, sl8=tid&7) loads uint4 (8 bf16) x4 per matrix per sub,
// writes b64 pairs to LDS (pitch 134 u32: 8B aligned, <=2-way banks), and
// accumulates sum of squares for its fixed row. Compute: 8x8 lanes x 4x4 rows,
// 4 px per iteration via uint2 LDS reads. fp32 acc -> LDS atomics -> global.
// ============================================================================
#define K2P 134
__global__ __launch_bounds__(256) void k2_gram(
    const u16* __restrict__ qw, const u16* __restrict__ kw,
    float* __restrict__ G, float* __restrict__ ssq)
{
    const int chunk = blockIdx.x, j = blockIdx.y, b = blockIdx.z;
    const int tid = threadIdx.x, wv = tid >> 6, lane = tid & 63;
    const int li = lane >> 3, lj = lane & 7;
    __shared__ u32 qb[32 * K2P];
    __shared__ u32 kb[32 * K2P];
    __shared__ float Gl[1024];
    for (int e = tid; e < K2P; e += 256) { qb[31 * K2P + e] = 0; kb[31 * K2P + e] = 0; }
    for (int e = tid; e < 1024; e += 256) Gl[e] = 0.f;

    const int srow = tid >> 3, sl8 = tid & 7;
    float sq = 0.f, sk = 0.f;
    float acc[4][4];
    #pragma unroll
    for (int a = 0; a < 4; a++)
        #pragma unroll
        for (int bb = 0; bb < 4; bb++) acc[a][bb] = 0.f;

    const u32* qg = (const u32*)qw;
    const u32* kg = (const u32*)kw;
    for (int sub = 0; sub < 4; sub++) {
        __syncthreads();
        if (srow < 31) {
            const size_t base = ((size_t)b * NCH + 16 * srow + j) * 8192 + chunk * 512 + sub * 128;
            #pragma unroll
            for (int i = 0; i < 4; i++) {
                const int co = (sl8 + 8 * i) * 4;
                uint4 v = *(const uint4*)(qg + base + co);
                *(uint2*)&qb[srow * K2P + co]     = make_uint2(v.x, v.y);
                *(uint2*)&qb[srow * K2P + co + 2] = make_uint2(v.z, v.w);
                sq = fmaf(bfl(v.x), bfl(v.x), sq); sq = fmaf(bfh(v.x), bfh(v.x), sq);
                sq = fmaf(bfl(v.y), bfl(v.y), sq); sq = fmaf(bfh(v.y), bfh(v.y), sq);
                sq = fmaf(bfl(v.z), bfl(v.z), sq); sq = fmaf(bfh(v.z), bfh(v.z), sq);
                sq = fmaf(bfl(v.w), bfl(v.w), sq); sq = fmaf(bfh(v.w), bfh(v.w), sq);
                uint4 u = *(const uint4*)(kg + base + co);
                *(uint2*)&kb[srow * K2P + co]     = make_uint2(u.x, u.y);
                *(uint2*)&kb[srow * K2P + co + 2] = make_uint2(u.z, u.w);
                sk = fmaf(bfl(u.x), bfl(u.x), sk); sk = fmaf(bfh(u.x), bfh(u.x), sk);
                sk = fmaf(bfl(u.y), bfl(u.y), sk); sk = fmaf(bfh(u.y), bfh(u.y), sk);
                sk = fmaf(bfl(u.z), bfl(u.z), sk); sk = fmaf(bfh(u.z), bfh(u.z), sk);
                sk = fmaf(bfl(u.w), bfl(u.w), sk); sk = fmaf(bfh(u.w), bfh(u.w), sk);
            }
        }
        __syncthreads();
        const int c0 = wv * 32;               // 64 px (32 u32) per wave
        #pragma unroll 2
        for (int s2 = 0; s2 < 16; s2++) {
            const int col = c0 + 2 * s2;
            float qf[4][4], kf[4][4];
            #pragma unroll
            for (int a = 0; a < 4; a++) {
                const uint2 qv = *(const uint2*)&qb[(4 * li + a) * K2P + col];
                qf[a][0] = bfl(qv.x); qf[a][1] = bfh(qv.x);
                qf[a][2] = bfl(qv.y); qf[a][3] = bfh(qv.y);
                const uint2 kv = *(const uint2*)&kb[(4 * lj + a) * K2P + col];
                kf[a][0] = bfl(kv.x); kf[a][1] = bfh(kv.x);
                kf[a][2] = bfl(kv.y); kf[a][3] = bfh(kv.y);
            }
            #pragma unroll
            for (int a = 0; a < 4; a++)
                #pragma unroll
                for (int bb = 0; bb < 4; bb++)
                    acc[a][bb] += qf[a][0] * kf[bb][0] + qf[a][1] * kf[bb][1]
                                + qf[a][2] * kf[bb][2] + qf[a][3] * kf[bb][3];
        }
    }
    // ssq: reduce over the 8 staging lanes of each row, one atomic per row
    #pragma unroll
    for (int d = 1; d < 8; d <<= 1) { sq += __shfl_xor(sq, d, 64); sk += __shfl_xor(sk, d, 64); }
    if (sl8 == 0 && srow < 31) {
        atomicAdd(&ssq[((size_t)b * 2 + 0) * NCH + 16 * srow + j], sq);
        atomicAdd(&ssq[((size_t)b * 2 + 1) * NCH + 16 * srow + j], sk);
    }
    __syncthreads();
    #pragma unroll
    for (int a = 0; a < 4; a++)
        #pragma unroll
        for (int bb = 0; bb < 4; bb++)
            atomicAdd(&Gl[(4 * li + a) * 32 + 4 * lj + bb], acc[a][bb]);
    __syncthreads();
    for (int e = tid; e < 1024; e += 256) {
        int r1 = e >> 5, r2 = e & 31;
        if (r1 < 31 && r2 < 31)
            atomicAdd(&G[((size_t)b * 31 + r1) * 31 + r2], Gl[e]);
    }
}

// ============================================================================
// K3: norms + softmax -> attn[b][31][31]. Single tiny block.
// ============================================================================
__global__ void k3_softmax(const float* __restrict__ G, const float* __restrict__ ssq,
                           const float* __restrict__ temp, float* __restrict__ attn)
{
    const int tid = threadIdx.x;
    __shared__ float nl[4][2][31];
    if (tid < 248) {
        int b = tid / 62, rem = tid % 62, g = rem / 31, r = rem % 31;
        float s = 0.f;
        for (int jj = 0; jj < 16; jj++)
            s += ssq[((size_t)b * 2 + g) * NCH + 16 * r + jj];
        nl[b][g][r] = fmaxf(sqrtf(s), 1e-12f);
    }
    __syncthreads();
    if (tid < 124) {
        int b = tid / 31, r1 = tid % 31;
        float t = temp[0];
        float lg[31];
        float mx = -1e30f;
        for (int r2 = 0; r2 < 31; r2++) {
            lg[r2] = G[((size_t)b * 31 + r1) * 31 + r2] * t /
                     (nl[b][0][r1] * nl[b][1][r2]);
            mx = fmaxf(mx, lg[r2]);
        }
        float sum = 0.f;
        for (int r2 = 0; r2 < 31; r2++) { lg[r2] = expf(lg[r2] - mx); sum += lg[r2]; }
        float inv = 1.f / sum;
        for (int r2 = 0; r2 < 31; r2++)
            attn[((size_t)b * 31 + r1) * 31 + r2] = lg[r2] * inv;
    }
}

// ============================================================================
// K4a: out = attn @ V in row space (31x31 per (j,px)). Thread = 4 px.
// ============================================================================
__global__ __launch_bounds__(256) void k4a_av(
    const u16* __restrict__ vw, const float* __restrict__ attn, u16* __restrict__ outw)
{
    const int j = blockIdx.y, b = blockIdx.z;
    const int px = (blockIdx.x * 256 + threadIdx.x) * 4;
    uint2 vv[31];
    #pragma unroll
    for (int r2 = 0; r2 < 31; r2++)
        vv[r2] = *(const uint2*)(vw + ((size_t)b * NCH + 16 * r2 + j) * HW + px);
    const float* at = attn + (size_t)b * 961;
    #pragma unroll
    for (int half = 0; half < 2; half++) {
        const int nr = half ? 15 : 16;
        float acc[16][4];
        #pragma unroll
        for (int r1 = 0; r1 < 16; r1++)
            #pragma unroll
            for (int p = 0; p < 4; p++) acc[r1][p] = 0.f;
        #pragma unroll 2
        for (int r2 = 0; r2 < 31; r2++) {
            float v0 = bfl(vv[r2].x), v1 = bfh(vv[r2].x);
            float v2 = bfl(vv[r2].y), v3 = bfh(vv[r2].y);
            #pragma unroll
            for (int r1 = 0; r1 < 16; r1++) {
                if (r1 < nr) {
                    float a = at[(half * 16 + r1) * 31 + r2];
                    acc[r1][0] = fmaf(a, v0, acc[r1][0]);
                    acc[r1][1] = fmaf(a, v1, acc[r1][1]);
                    acc[r1][2] = fmaf(a, v2, acc[r1][2]);
                    acc[r1][3] = fmaf(a, v3, acc[r1][3]);
                }
            }
        }
        #pragma unroll
        for (int r1 = 0; r1 < 16; r1++) {
            if (r1 < nr) {
                uint2 st;
                st.x = (u32)f2bf(acc[r1][0]) | ((u32)f2bf(acc[r1][1]) << 16);
                st.y = (u32)f2bf(acc[r1][2]) | ((u32)f2bf(acc[r1][3]) << 16);
                *(uint2*)(outw + ((size_t)b * NCH + 16 * (half * 16 + r1) + j) * HW + px) = st;
            }
        }
    }
}

// ============================================================================
// K4b: final projection: fin[o*31+c] = sum_t wp[o][t] * out[t*31+c], per pixel.
// ============================================================================
__global__ __launch_bounds__(256) void k4b_proj(
    const u16* __restrict__ outw, const float* __restrict__ wp, float* __restrict__ fin)
{
    const int c = blockIdx.y, b = blockIdx.z;
    const int px = (blockIdx.x * 256 + threadIdx.x) * 4;
    float acc[16][4];
    #pragma unroll
    for (int o = 0; o < 16; o++)
        #pragma unroll
        for (int p = 0; p < 4; p++) acc[o][p] = 0.f;
    #pragma unroll 2
    for (int t = 0; t < 16; t++) {
        uint2 ov = *(const uint2*)(outw + ((size_t)b * NCH + t * 31 + c) * HW + px);
        float v0 = bfl(ov.x), v1 = bfh(ov.x), v2 = bfl(ov.y), v3 = bfh(ov.y);
        #pragma unroll
        for (int o = 0; o < 16; o++) {
            float w = wp[o * 16 + t];
            acc[o][0] = fmaf(w, v0, acc[o][0]);
            acc[o][1] = fmaf(w, v1, acc[o][1]);
            acc[o][2] = fmaf(w, v2, acc[o][2]);
            acc[o][3] = fmaf(w, v3, acc[o][3]);
        }
    }
    #pragma unroll
    for (int o = 0; o < 16; o++) {
        float4 st = make_float4(acc[o][0], acc[o][1], acc[o][2], acc[o][3]);
        *(float4*)(fin + ((size_t)b * NCH + o * 31 + c) * HW + px) = st;
    }
}

extern "C" void kernel_launch(void* const* d_in, const int* in_sizes, int n_in,
                              void* d_out, int out_size, void* d_ws, size_t ws_size,
                              hipStream_t stream)
{
    (void)in_sizes; (void)n_in; (void)out_size; (void)ws_size;
    const float* x  = (const float*)d_in[0];
    const float* wq = (const float*)d_in[1];
    const float* wd = (const float*)d_in[2];
    const float* wp = (const float*)d_in[3];
    const float* tp = (const float*)d_in[4];
    float* fin = (float*)d_out;
    char* ws = (char*)d_ws;

    const size_t SZB = (size_t)4 * NCH * HW * 2;   // 65,011,712 bytes per bf16 tensor
    u16* qw   = (u16*)(ws);
    u16* kw   = (u16*)(ws + SZB);
    u16* vw   = (u16*)(ws + 2 * SZB);
    u16* outw = qw;   // q is dead after K2; same-stream ordering makes aliasing safe
    float* G    = (float*)(ws + 3 * SZB);            // 4*31*31 fp32 (16KB slot)
    float* ssq  = (float*)(ws + 3 * SZB + 16384);    // 4*2*496 fp32 (16KB slot)
    float* attn = (float*)(ws + 3 * SZB + 32768);    // 4*31*31 fp32

    // zero the atomic accumulators (ws is poisoned 0xAA before every launch)
    hipMemsetAsync(ws + 3 * SZB, 0, 32768, stream);

    k1_qkvdw<<<dim3(22, 31, 4), 256, 0, stream>>>(x, wq, wd, qw, kw, vw);
    k2_gram<<<dim3(16, 16, 4), 256, 0, stream>>>(qw, kw, G, ssq);
    k3_softmax<<<dim3(1, 1, 1), 256, 0, stream>>>(G, ssq, tp, attn);
    k4a_av<<<dim3(16, 16, 4), 256, 0, stream>>>(vw, attn, outw);
    k4b_proj<<<dim3(16, 31, 4), 256, 0, stream>>>(outw, wp, fin);
}

// Round 6
// 576.733 us; speedup vs baseline: 1.0988x; 1.0988x over previous
//
#include <hip/hip_runtime.h>
#include <hip/hip_bf16.h>

typedef unsigned int u32;
typedef unsigned short u16;

// ---- bf16 helpers (fp32 <-> bf16 with RNE) ----
__device__ __forceinline__ float bfl(u32 v) { return __uint_as_float(v << 16); }
__device__ __forceinline__ float bfh(u32 v) { return __uint_as_float(v & 0xffff0000u); }
__device__ __forceinline__ u16 f2bf(float f) {
    u32 u = __float_as_uint(f);
    u32 r = (u + 0x7fffu + ((u >> 16) & 1u)) >> 16;
    return (u16)r;
}

#define HW 16384          // 128*128
#define NCH 496           // 16*31 combined channels (m = t*31 + c)

// ============================================================================
// K1 v3.1: fused pointwise qkv (16->48) + depthwise 3x3 per (b,c) plane.
// Block = 6-output-row x 128-col strip; 256 threads as 2 rows x 128 cols.
// 8 halo rows of x in registers (xv[4][16]). Per (group g, quad-pair qp):
// stage 8 channels' pointwise in LDS float4[2][8][130] -- COLUMN HALO (cols
// 0/129 zeroed once) so depthwise reads are unconditional prow[tc+dx]: kills
// ~900 edge-select VALU ops/thread (round-5: VALUBusy 40% with ~2x instr
// overhead vs FMA count; barriers proven cheap, occupancy knobs proven dead).
// ============================================================================
__global__ __launch_bounds__(256) void k1_qkvdw(
    const float* __restrict__ x, const float* __restrict__ wq,
    const float* __restrict__ wd, u16* __restrict__ qw, u16* __restrict__ kw,
    u16* __restrict__ vw)
{
    const int s = blockIdx.x, c = blockIdx.y, b = blockIdx.z;
    const int tid = threadIdx.x;
    const int tr = tid >> 7, tc = tid & 127;
    const int r0 = s * 6 - 1;                 // first halo row

    __shared__ float4 pws[2][8][130];         // 33.3 KB, cols 0/129 = conv pad

    // one-time zero of the column halo (visible after first post-write barrier)
    if (tid < 32) {
        const int lq = tid >> 4, row = (tid >> 1) & 7, col = (tid & 1) * 129;
        pws[lq][row][col] = make_float4(0.f, 0.f, 0.f, 0.f);
    }

    // load 8 halo rows (2 per slot) x 16 channels of x
    float xv[4][16];
    #pragma unroll
    for (int sl = 0; sl < 4; sl++) {
        const int row = r0 + 2 * sl + tr;
        const bool ok = (row >= 0) && (row < 128);
        const float* xp = x + ((size_t)b * 496 + c) * HW + row * 128 + tc;
        #pragma unroll
        for (int t = 0; t < 16; t++)
            xv[sl][t] = ok ? xp[(size_t)t * 31 * HW] : 0.f;
    }

    for (int g = 0; g < 3; g++) {
        u16* dst = (g == 0) ? qw : (g == 1) ? kw : vw;
        for (int qp = 0; qp < 2; qp++) {
            __syncthreads();                  // prior depthwise reads complete
            // pointwise for 8 channels (quads 2qp, 2qp+1) at the 8 halo rows
            #pragma unroll
            for (int sl = 0; sl < 4; sl++) {
                float pv[8];
                #pragma unroll
                for (int o8 = 0; o8 < 8; o8++) {
                    const int oo = qp * 8 + o8;
                    float a = 0.f;
                    #pragma unroll
                    for (int ci = 0; ci < 16; ci++)
                        a = fmaf(wq[(g * 16 + oo) * 16 + ci], xv[sl][ci], a);
                    pv[o8] = a;
                }
                const int lr = 2 * sl + tr;
                pws[0][lr][tc + 1] = make_float4(pv[0], pv[1], pv[2], pv[3]);
                pws[1][lr][tc + 1] = make_float4(pv[4], pv[5], pv[6], pv[7]);
            }
            __syncthreads();

            // depthwise 3x3 at the 6 output rows (3 per thread-row)
            #pragma unroll
            for (int k = 0; k < 3; k++) {
                const int lr = 1 + 2 * k + tr;    // 1..6 local halo row
                const int grow = r0 + lr;         // global output row
                if (grow < 128) {                 // trims only the last strip
                    #pragma unroll
                    for (int lq = 0; lq < 2; lq++) {
                        const int q4 = qp * 2 + lq;
                        const int o0 = g * 16 + q4 * 4;
                        float a0 = 0.f, a1 = 0.f, a2 = 0.f, a3 = 0.f;
                        #pragma unroll
                        for (int dy = 0; dy < 3; dy++) {
                            const float4* prow = &pws[lq][lr + dy - 1][0];
                            const float4 Lv = prow[tc];
                            const float4 Cv = prow[tc + 1];
                            const float4 Rv = prow[tc + 2];
                            const int kb9 = dy * 3;
                            a0 = fmaf(Lv.x, wd[(o0+0)*9+kb9+0], fmaf(Cv.x, wd[(o0+0)*9+kb9+1], fmaf(Rv.x, wd[(o0+0)*9+kb9+2], a0)));
                            a1 = fmaf(Lv.y, wd[(o0+1)*9+kb9+0], fmaf(Cv.y, wd[(o0+1)*9+kb9+1], fmaf(Rv.y, wd[(o0+1)*9+kb9+2], a1)));
                            a2 = fmaf(Lv.z, wd[(o0+2)*9+kb9+0], fmaf(Cv.z, wd[(o0+2)*9+kb9+1], fmaf(Rv.z, wd[(o0+2)*9+kb9+2], a2)));
                            a3 = fmaf(Lv.w, wd[(o0+3)*9+kb9+0], fmaf(Cv.w, wd[(o0+3)*9+kb9+1], fmaf(Rv.w, wd[(o0+3)*9+kb9+2], a3)));
                        }
                        const size_t pbase = (size_t)grow * 128 + tc;
                        dst[((size_t)b * NCH + (q4*4+0) * 31 + c) * HW + pbase] = f2bf(a0);
                        dst[((size_t)b * NCH + (q4*4+1) * 31 + c) * HW + pbase] = f2bf(a1);
                        dst[((size_t)b * NCH + (q4*4+2) * 31 + c) * HW + pbase] = f2bf(a2);
                        dst[((size_t)b * NCH + (q4*4+3) * 31 + c) * HW + pbase] = f2bf(a3);
                    }
                }
            }
        }
    }
}

// ============================================================================
// K2 v2: Gram G[b][31][31] = Q K^T over N=262144, plus ssq (L2-norm numerators)
// accumulated during staging. Unchanged from round 3 (no counters yet).
// ============================================================================
#define K2P 134
__global__ __launch_bounds__(256) void k2_gram(
    const u16* __restrict__ qw, const u16* __restrict__ kw,
    float* __restrict__ G, float* __restrict__ ssq)
{
    const int chunk = blockIdx.x, j = blockIdx.y, b = blockIdx.z;
    const int tid = threadIdx.x, wv = tid >> 6, lane = tid & 63;
    const int li = lane >> 3, lj = lane & 7;
    __shared__ u32 qb[32 * K2P];
    __shared__ u32 kb[32 * K2P];
    __shared__ float Gl[1024];
    for (int e = tid; e < K2P; e += 256) { qb[31 * K2P + e] = 0; kb[31 * K2P + e] = 0; }
    for (int e = tid; e < 1024; e += 256) Gl[e] = 0.f;

    const int srow = tid >> 3, sl8 = tid & 7;
    float sq = 0.f, sk = 0.f;
    float acc[4][4];
    #pragma unroll
    for (int a = 0; a < 4; a++)
        #pragma unroll
        for (int bb = 0; bb < 4; bb++) acc[a][bb] = 0.f;

    const u32* qg = (const u32*)qw;
    const u32* kg = (const u32*)kw;
    for (int sub = 0; sub < 4; sub++) {
        __syncthreads();
        if (srow < 31) {
            const size_t base = ((size_t)b * NCH + 16 * srow + j) * 8192 + chunk * 512 + sub * 128;
            #pragma unroll
            for (int i = 0; i < 4; i++) {
                const int co = (sl8 + 8 * i) * 4;
                uint4 v = *(const uint4*)(qg + base + co);
                *(uint2*)&qb[srow * K2P + co]     = make_uint2(v.x, v.y);
                *(uint2*)&qb[srow * K2P + co + 2] = make_uint2(v.z, v.w);
                sq = fmaf(bfl(v.x), bfl(v.x), sq); sq = fmaf(bfh(v.x), bfh(v.x), sq);
                sq = fmaf(bfl(v.y), bfl(v.y), sq); sq = fmaf(bfh(v.y), bfh(v.y), sq);
                sq = fmaf(bfl(v.z), bfl(v.z), sq); sq = fmaf(bfh(v.z), bfh(v.z), sq);
                sq = fmaf(bfl(v.w), bfl(v.w), sq); sq = fmaf(bfh(v.w), bfh(v.w), sq);
                uint4 u = *(const uint4*)(kg + base + co);
                *(uint2*)&kb[srow * K2P + co]     = make_uint2(u.x, u.y);
                *(uint2*)&kb[srow * K2P + co + 2] = make_uint2(u.z, u.w);
                sk = fmaf(bfl(u.x), bfl(u.x), sk); sk = fmaf(bfh(u.x), bfh(u.x), sk);
                sk = fmaf(bfl(u.y), bfl(u.y), sk); sk = fmaf(bfh(u.y), bfh(u.y), sk);
                sk = fmaf(bfl(u.z), bfl(u.z), sk); sk = fmaf(bfh(u.z), bfh(u.z), sk);
                sk = fmaf(bfl(u.w), bfl(u.w), sk); sk = fmaf(bfh(u.w), bfh(u.w), sk);
            }
        }
        __syncthreads();
        const int c0 = wv * 32;               // 64 px (32 u32) per wave
        #pragma unroll 2
        for (int s2 = 0; s2 < 16; s2++) {
            const int col = c0 + 2 * s2;
            float qf[4][4], kf[4][4];
            #pragma unroll
            for (int a = 0; a < 4; a++) {
                const uint2 qv = *(const uint2*)&qb[(4 * li + a) * K2P + col];
                qf[a][0] = bfl(qv.x); qf[a][1] = bfh(qv.x);
                qf[a][2] = bfl(qv.y); qf[a][3] = bfh(qv.y);
                const uint2 kv = *(const uint2*)&kb[(4 * lj + a) * K2P + col];
                kf[a][0] = bfl(kv.x); kf[a][1] = bfh(kv.x);
                kf[a][2] = bfl(kv.y); kf[a][3] = bfh(kv.y);
            }
            #pragma unroll
            for (int a = 0; a < 4; a++)
                #pragma unroll
                for (int bb = 0; bb < 4; bb++)
                    acc[a][bb] += qf[a][0] * kf[bb][0] + qf[a][1] * kf[bb][1]
                                + qf[a][2] * kf[bb][2] + qf[a][3] * kf[bb][3];
        }
    }
    // ssq: reduce over the 8 staging lanes of each row, one atomic per row
    #pragma unroll
    for (int d = 1; d < 8; d <<= 1) { sq += __shfl_xor(sq, d, 64); sk += __shfl_xor(sk, d, 64); }
    if (sl8 == 0 && srow < 31) {
        atomicAdd(&ssq[((size_t)b * 2 + 0) * NCH + 16 * srow + j], sq);
        atomicAdd(&ssq[((size_t)b * 2 + 1) * NCH + 16 * srow + j], sk);
    }
    __syncthreads();
    #pragma unroll
    for (int a = 0; a < 4; a++)
        #pragma unroll
        for (int bb = 0; bb < 4; bb++)
            atomicAdd(&Gl[(4 * li + a) * 32 + 4 * lj + bb], acc[a][bb]);
    __syncthreads();
    for (int e = tid; e < 1024; e += 256) {
        int r1 = e >> 5, r2 = e & 31;
        if (r1 < 31 && r2 < 31)
            atomicAdd(&G[((size_t)b * 31 + r1) * 31 + r2], Gl[e]);
    }
}

// ============================================================================
// K3: norms + softmax -> attn[b][31][31]. Single tiny block.
// ============================================================================
__global__ void k3_softmax(const float* __restrict__ G, const float* __restrict__ ssq,
                           const float* __restrict__ temp, float* __restrict__ attn)
{
    const int tid = threadIdx.x;
    __shared__ float nl[4][2][31];
    if (tid < 248) {
        int b = tid / 62, rem = tid % 62, g = rem / 31, r = rem % 31;
        float s = 0.f;
        for (int jj = 0; jj < 16; jj++)
            s += ssq[((size_t)b * 2 + g) * NCH + 16 * r + jj];
        nl[b][g][r] = fmaxf(sqrtf(s), 1e-12f);
    }
    __syncthreads();
    if (tid < 124) {
        int b = tid / 31, r1 = tid % 31;
        float t = temp[0];
        float lg[31];
        float mx = -1e30f;
        for (int r2 = 0; r2 < 31; r2++) {
            lg[r2] = G[((size_t)b * 31 + r1) * 31 + r2] * t /
                     (nl[b][0][r1] * nl[b][1][r2]);
            mx = fmaxf(mx, lg[r2]);
        }
        float sum = 0.f;
        for (int r2 = 0; r2 < 31; r2++) { lg[r2] = expf(lg[r2] - mx); sum += lg[r2]; }
        float inv = 1.f / sum;
        for (int r2 = 0; r2 < 31; r2++)
            attn[((size_t)b * 31 + r1) * 31 + r2] = lg[r2] * inv;
    }
}

// ============================================================================
// K4 fused (replaces k4a + k4b): per (32-px tile, b):
//  stage v[496][32] bf16 in LDS (pitch 36 u16 -> <=2-way banks, 35.7 KB);
//  phase 1: out[m=16r+j] = sum_r2 attn[r][r2] v[16r2+j]  -> packed bf16 regs
//           (attn row index wave-uniform -> readfirstlane -> s_load path);
//  barrier; overwrite the v buffer with out; barrier;
//  phase 2: fin[o*31+c] = sum_t wp[o][t] out[t*31+c], fp32 coalesced stores.
// Saves the 130 MB out round-trip (k4 stage: 325 -> 195 MB HBM) + one launch.
// ============================================================================
__global__ __launch_bounds__(256) void k4_fused(
    const u16* __restrict__ vw, const float* __restrict__ attn,
    const float* __restrict__ wp, float* __restrict__ fin)
{
    const int pt = blockIdx.x, b = blockIdx.y;
    const int tid = threadIdx.x;
    const int px0 = pt * 32;
    const int p8 = tid & 7;          // px quad index (4 px each)
    const int mrow = tid >> 3;       // 0..31 (wave-contiguous groups of 8)
    __shared__ u16 vs[496][36];      // pitch 36 u16 = 72 B (8B-aligned rows)

    // stage v[496][32 px]: 8 lanes x uint2(4 px) per row, 8 rows per wave
    {
        const u16* vb = vw + (size_t)b * NCH * HW + px0;
        #pragma unroll
        for (int i = 0; i < 16; i++) {
            const int row = mrow + 32 * i;    // 0..511
            if (row < NCH)
                *(uint2*)&vs[row][p8 * 4] = *(const uint2*)(vb + (size_t)row * HW + p8 * 4);
        }
    }
    __syncthreads();

    // phase 1: out rows (m = 16r + j) into packed-bf16 registers
    u32 pk[32];
    const float* at = attn + (size_t)b * 961;
    #pragma unroll
    for (int i = 0; i < 16; i++) {
        const int m = mrow + 32 * i;
        if (m < NCH) {                                    // wave-uniform branch
            const int r = __builtin_amdgcn_readfirstlane(m >> 4);  // uniform per wave
            const int j = m & 15;
            float a0 = 0.f, a1 = 0.f, a2 = 0.f, a3 = 0.f;
            for (int r2 = 0; r2 < 31; r2++) {
                const float w = at[r * 31 + r2];          // s_load (uniform)
                const uint2 vv = *(const uint2*)&vs[16 * r2 + j][p8 * 4];
                a0 = fmaf(w, bfl(vv.x), a0);
                a1 = fmaf(w, bfh(vv.x), a1);
                a2 = fmaf(w, bfl(vv.y), a2);
                a3 = fmaf(w, bfh(vv.y), a3);
            }
            pk[2*i]   = (u32)f2bf(a0) | ((u32)f2bf(a1) << 16);
            pk[2*i+1] = (u32)f2bf(a2) | ((u32)f2bf(a3) << 16);
        }
    }
    __syncthreads();   // all v reads done -> safe to overwrite
    #pragma unroll
    for (int i = 0; i < 16; i++) {
        const int m = mrow + 32 * i;
        if (m < NCH)
            *(uint2*)&vs[m][p8 * 4] = make_uint2(pk[2*i], pk[2*i+1]);
    }
    __syncthreads();

    // phase 2: final 16x16 projection, fp32 stores (8 lanes x 16B = 128 B/row)
    float* fb = fin + (size_t)b * NCH * HW + px0;
    #pragma unroll
    for (int i = 0; i < 16; i++) {
        const int n = mrow + 32 * i;
        if (n < NCH) {
            const int o = (n * 2115) >> 16;   // n / 31 for n < 496
            const int c = n - o * 31;
            float a0 = 0.f, a1 = 0.f, a2 = 0.f, a3 = 0.f;
            #pragma unroll
            for (int t = 0; t < 16; t++) {
                const float w = wp[o * 16 + t];
                const uint2 ov = *(const uint2*)&vs[t * 31 + c][p8 * 4];
                a0 = fmaf(w, bfl(ov.x), a0);
                a1 = fmaf(w, bfh(ov.x), a1);
                a2 = fmaf(w, bfl(ov.y), a2);
                a3 = fmaf(w, bfh(ov.y), a3);
            }
            *(float4*)(fb + (size_t)n * HW + p8 * 4) = make_float4(a0, a1, a2, a3);
        }
    }
}

extern "C" void kernel_launch(void* const* d_in, const int* in_sizes, int n_in,
                              void* d_out, int out_size, void* d_ws, size_t ws_size,
                              hipStream_t stream)
{
    (void)in_sizes; (void)n_in; (void)out_size; (void)ws_size;
    const float* x  = (const float*)d_in[0];
    const float* wq = (const float*)d_in[1];
    const float* wd = (const float*)d_in[2];
    const float* wp = (const float*)d_in[3];
    const float* tp = (const float*)d_in[4];
    float* fin = (float*)d_out;
    char* ws = (char*)d_ws;

    const size_t SZB = (size_t)4 * NCH * HW * 2;   // 65,011,712 bytes per bf16 tensor
    u16* qw   = (u16*)(ws);
    u16* kw   = (u16*)(ws + SZB);
    u16* vw   = (u16*)(ws + 2 * SZB);
    float* G    = (float*)(ws + 3 * SZB);            // 4*31*31 fp32 (16KB slot)
    float* ssq  = (float*)(ws + 3 * SZB + 16384);    // 4*2*496 fp32 (16KB slot)
    float* attn = (float*)(ws + 3 * SZB + 32768);    // 4*31*31 fp32

    // zero the atomic accumulators (ws is poisoned 0xAA before every launch)
    hipMemsetAsync(ws + 3 * SZB, 0, 32768, stream);

    k1_qkvdw<<<dim3(22, 31, 4), 256, 0, stream>>>(x, wq, wd, qw, kw, vw);
    k2_gram<<<dim3(16, 16, 4), 256, 0, stream>>>(qw, kw, G, ssq);
    k3_softmax<<<dim3(1, 1, 1), 256, 0, stream>>>(G, ssq, tp, attn);
    k4_fused<<<dim3(512, 4), 256, 0, stream>>>(vw, attn, wp, fin);
}